// Round 9
// baseline (1452.988 us; speedup 1.0000x reference)
//
#include <hip/hip_runtime.h>

#define SEQ 2048
#define DH  64
#define NH  16
#define NB  4
#define NHEADS (NB * NH)            // 64
#define NKT 32                      // k-tiles of 64 keys
#define QT  64                      // q-rows per block
#define NQT (SEQ / QT)              // 32 q-tiles per head
#define NBLK (NHEADS * NQT)         // 2048 blocks
#define KTILE_SH 8192               // shorts per K/V tile image (64x64 hi+lo)

typedef _Float16 f16x8 __attribute__((ext_vector_type(8)));
typedef _Float16 f16x4 __attribute__((ext_vector_type(4)));
typedef short    s16x8 __attribute__((ext_vector_type(8)));
typedef float    f32x4 __attribute__((ext_vector_type(4)));

#define MF32(a,b,c) __builtin_amdgcn_mfma_f32_16x16x32_f16(a,b,c,0,0,0)
#define MF16(a,b,c) __builtin_amdgcn_mfma_f32_16x16x16f16(a,b,c,0,0,0)

static __device__ __forceinline__ short f16b(float x) {
    _Float16 h = (_Float16)x;
    return __builtin_bit_cast(short, h);
}

// ------------- prep: pack K,V into fragment-ordered f16 hi/lo images -------------
// kimg tile: [kg 4][dh 2][hl 2][lane 64][8]   (A-frag of swapped QK: row=key=lj, k=d)
// vimg tile: [kc 4][dt 4][lane 64][hi 4 | lo 4]  (B-frag of PV: col=d=lj, k=lg*4+j)
__global__ __launch_bounds__(256) void prep(
    const float* __restrict__ K, const float* __restrict__ V,
    const int* __restrict__ pad,
    short* __restrict__ kimg, short* __restrict__ vimg, unsigned* __restrict__ pm)
{
    const int t    = threadIdx.x;
    const int kt   = blockIdx.x & (NKT - 1);
    const int head = blockIdx.x >> 5;
    const size_t rowbase = ((size_t)head * SEQ + (size_t)kt * 64) * DH;

    {   // ---- K frag-pack: thread owns (row = t>>2, 16 cols) ----
        const int row = t >> 2;
        const int c0  = (t & 3) * 16;
        const int lj  = row & 15;
        const float4* gp = (const float4*)(K + rowbase + (size_t)row * DH + c0);
        const float4 v0 = gp[0], v1 = gp[1], v2 = gp[2], v3 = gp[3];
        const float x[16] = {v0.x,v0.y,v0.z,v0.w, v1.x,v1.y,v1.z,v1.w,
                             v2.x,v2.y,v2.z,v2.w, v3.x,v3.y,v3.z,v3.w};
        short* tb = kimg + ((size_t)head * NKT + kt) * KTILE_SH + (row >> 4) * 2048;
#pragma unroll
        for (int cg = 0; cg < 2; ++cg) {
            const int col0 = c0 + cg * 8;
            const int dh = col0 >> 5, lg = (col0 & 31) >> 3;
            s16x8 hi8, lo8;
#pragma unroll
            for (int j = 0; j < 8; ++j) {
                const float xv = x[cg * 8 + j];
                _Float16 h = (_Float16)xv;
                hi8[j] = __builtin_bit_cast(short, h);
                lo8[j] = f16b(xv - (float)h);
            }
            *(s16x8*)&tb[dh * 1024 +       (lg * 16 + lj) * 8] = hi8;
            *(s16x8*)&tb[dh * 1024 + 512 + (lg * 16 + lj) * 8] = lo8;
        }
    }
    {   // ---- V frag-pack: thread = (kc = t>>6, lane l = t&63) ----
        const int kc = t >> 6, l = t & 63;
        const int lg = l >> 4, lj = l & 15;
        short* tb = vimg + ((size_t)head * NKT + kt) * KTILE_SH + kc * 2048;
#pragma unroll
        for (int dt = 0; dt < 4; ++dt) {
            s16x8 o;
#pragma unroll
            for (int j = 0; j < 4; ++j) {
                const float xv = V[rowbase + (size_t)(kc * 16 + lg * 4 + j) * DH + dt * 16 + lj];
                _Float16 h = (_Float16)xv;
                o[j]     = __builtin_bit_cast(short, h);
                o[4 + j] = f16b(xv - (float)h);
            }
            *(s16x8*)&tb[dt * 512 + l * 8] = o;
        }
    }
    if (blockIdx.x == 0) {   // pad bitmask: pm[b*64 + key_local] bit kt
        const int b = t >> 6, klc = t & 63;
        unsigned mword = 0;
#pragma unroll
        for (int kt2 = 0; kt2 < NKT; ++kt2)
            mword |= (unsigned)(pad[b * SEQ + kt2 * 64 + klc] & 1) << kt2;
        pm[t] = mword;
    }
}

struct KF { f16x8 h0, l0, h1, l1; };
struct VF { f16x8 v0, v1, v2, v3; };

#define LDKF(dst_, kt_) do {                                                   \
    const short* p_ = kb + (size_t)(kt_) * KTILE_SH;                           \
    dst_.h0 = *(const f16x8*)(p_ +        l * 8);                              \
    dst_.l0 = *(const f16x8*)(p_ +  512 + l * 8);                              \
    dst_.h1 = *(const f16x8*)(p_ + 1024 + l * 8);                              \
    dst_.l1 = *(const f16x8*)(p_ + 1536 + l * 8);                              \
} while (0)

#define LDVF(dst_, kt_) do {                                                   \
    const short* p_ = vb + (size_t)(kt_) * KTILE_SH;                           \
    dst_.v0 = *(const f16x8*)(p_ +        l * 8);                              \
    dst_.v1 = *(const f16x8*)(p_ +  512 + l * 8);                              \
    dst_.v2 = *(const f16x8*)(p_ + 1024 + l * 8);                              \
    dst_.v3 = *(const f16x8*)(p_ + 1536 + l * 8);                              \
} while (0)

// 24 MFMAs, 3-term split (kh*qh + kh*ql + kl*qh), 4 q-subtiles.
// SAME order in both passes (bitwise-equal e).
#define QK24(kf_, a0_, a1_, a2_, a3_) do {                                     \
    a0_ = MF32(kf_.h0, qh[0][0], a0_);  a1_ = MF32(kf_.h0, qh[1][0], a1_);     \
    a2_ = MF32(kf_.h0, qh[2][0], a2_);  a3_ = MF32(kf_.h0, qh[3][0], a3_);     \
    a0_ = MF32(kf_.h0, ql[0][0], a0_);  a1_ = MF32(kf_.h0, ql[1][0], a1_);     \
    a2_ = MF32(kf_.h0, ql[2][0], a2_);  a3_ = MF32(kf_.h0, ql[3][0], a3_);     \
    a0_ = MF32(kf_.l0, qh[0][0], a0_);  a1_ = MF32(kf_.l0, qh[1][0], a1_);     \
    a2_ = MF32(kf_.l0, qh[2][0], a2_);  a3_ = MF32(kf_.l0, qh[3][0], a3_);     \
    a0_ = MF32(kf_.h1, qh[0][1], a0_);  a1_ = MF32(kf_.h1, qh[1][1], a1_);     \
    a2_ = MF32(kf_.h1, qh[2][1], a2_);  a3_ = MF32(kf_.h1, qh[3][1], a3_);     \
    a0_ = MF32(kf_.h1, ql[0][1], a0_);  a1_ = MF32(kf_.h1, ql[1][1], a1_);     \
    a2_ = MF32(kf_.h1, ql[2][1], a2_);  a3_ = MF32(kf_.h1, ql[3][1], a3_);     \
    a0_ = MF32(kf_.l1, qh[0][1], a0_);  a1_ = MF32(kf_.l1, qh[1][1], a1_);     \
    a2_ = MF32(kf_.l1, qh[2][1], a2_);  a3_ = MF32(kf_.l1, qh[3][1], a3_);     \
} while (0)

#define P1BODY(kt_, kf_, vf_) do {                                             \
    f32x4 a0_ = (f32x4){0.f,0.f,0.f,0.f}, a1_ = (f32x4){0.f,0.f,0.f,0.f};      \
    f32x4 a2_ = (f32x4){0.f,0.f,0.f,0.f}, a3_ = (f32x4){0.f,0.f,0.f,0.f};      \
    QK24(kf_, a0_, a1_, a2_, a3_);                                             \
    const int kab_ = (kt_) * 64 + wk * 16 + lg * 4;                            \
    f16x4 w16_[4];                                                             \
    _Pragma("unroll") for (int m = 0; m < 4; ++m) {                            \
        const f32x4 av_ = (m==0) ? a0_ : (m==1) ? a1_ : (m==2) ? a2_ : a3_;    \
        const int qg_ = qglob + m * 16;                                        \
        float e_[4];                                                           \
        _Pragma("unroll") for (int r = 0; r < 4; ++r) {                        \
            const int ka_ = kab_ + r;                                          \
            const int pd_ = (int)((pmq[r] >> (kt_)) & 1u);                     \
            const bool msk_ = ((ka_ > qg_) != (pd_ == 1));                     \
            e_[r] = __expf((msk_ ? -8.0e9f : av_[r]) * 0.125f);                \
        }                                                                      \
        rs[m] += (e_[0] + e_[1]) + (e_[2] + e_[3]);                            \
        w16_[m] = (f16x4){(_Float16)e_[0], (_Float16)e_[1],                    \
                          (_Float16)e_[2], (_Float16)e_[3]};                   \
    }                                                                          \
    _Pragma("unroll") for (int dt = 0; dt < 4; ++dt) {                         \
        const f16x8 vv_ = (dt==0) ? vf_.v0 : (dt==1) ? vf_.v1                  \
                        : (dt==2) ? vf_.v2 : vf_.v3;                           \
        const f16x4 vh_ = __builtin_shufflevector(vv_, vv_, 0,1,2,3);          \
        const f16x4 vl_ = __builtin_shufflevector(vv_, vv_, 4,5,6,7);          \
        ov[0][dt] = MF16(w16_[0], vh_, ov[0][dt]);                             \
        ov[1][dt] = MF16(w16_[1], vh_, ov[1][dt]);                             \
        ov[2][dt] = MF16(w16_[2], vh_, ov[2][dt]);                             \
        ov[3][dt] = MF16(w16_[3], vh_, ov[3][dt]);                             \
        ov[0][dt] = MF16(w16_[0], vl_, ov[0][dt]);                             \
        ov[1][dt] = MF16(w16_[1], vl_, ov[1][dt]);                             \
        ov[2][dt] = MF16(w16_[2], vl_, ov[2][dt]);                             \
        ov[3][dt] = MF16(w16_[3], vl_, ov[3][dt]);                             \
    }                                                                          \
} while (0)

#define P2BODY(kt_, kf_) do {                                                  \
    f32x4 a0_ = (f32x4){0.f,0.f,0.f,0.f}, a1_ = (f32x4){0.f,0.f,0.f,0.f};      \
    f32x4 a2_ = (f32x4){0.f,0.f,0.f,0.f}, a3_ = (f32x4){0.f,0.f,0.f,0.f};      \
    QK24(kf_, a0_, a1_, a2_, a3_);                                             \
    const int kab_ = (kt_) * 64 + wk * 16 + lg * 4;                            \
    _Pragma("unroll") for (int m = 0; m < 4; ++m) {                            \
        const f32x4 av_ = (m==0) ? a0_ : (m==1) ? a1_ : (m==2) ? a2_ : a3_;    \
        const int qg_ = qglob + m * 16;                                        \
        float e_[4];                                                           \
        _Pragma("unroll") for (int r = 0; r < 4; ++r) {                        \
            const int ka_ = kab_ + r;                                          \
            const int pd_ = (int)((pmq[r] >> (kt_)) & 1u);                     \
            const bool msk_ = ((ka_ > qg_) != (pd_ == 1));                     \
            e_[r] = __expf((msk_ ? -8.0e9f : av_[r]) * 0.125f);                \
        }                                                                      \
        f32x4 w4_;                                                             \
        w4_[0] = e_[0] * invr[m]; w4_[1] = e_[1] * invr[m];                    \
        w4_[2] = e_[2] * invr[m]; w4_[3] = e_[3] * invr[m];                    \
        *(f32x4*)&out_w[wbm[m] + kab_] = w4_;   /* plain store: L2 merges */   \
    }                                                                          \
} while (0)

__global__ __launch_bounds__(256, 2) void attn_fwd(
    const float* __restrict__ Qf, const short* __restrict__ KI,
    const short* __restrict__ VI, const unsigned* __restrict__ PM,
    float* __restrict__ out_res, float* __restrict__ out_w)
{
    __shared__ float s_op[4][QT][65];    // per-wk O partials (epilogue) ~66.6 KB
    __shared__ float s_red[QT][4];       // rowsum partials

    const int t = threadIdx.x;
    int bid = blockIdx.x;
    bid = (bid & 7) * (NBLK / 8) + (bid >> 3);       // XCD-chunked swizzle (2048%8==0)

    const int qtile = bid & (NQT - 1);
    const int head  = bid >> 5;                      // b*NH + h
    const int q0    = qtile * QT;
    const size_t hoff = (size_t)head * SEQ * DH;
    const size_t woff = (size_t)head * SEQ * SEQ;

    const int l  = t & 63;
    const int wk = t >> 6;        // wave = 16-key column group 0..3
    const int lj = l & 15;
    const int lg = l >> 4;
    const int qglob = q0 + lj;    // q row for m=0 (lane-local in swapped layout)

    const short* kb = KI + (size_t)head * NKT * KTILE_SH + wk * 2048;
    const short* vb = VI + (size_t)head * NKT * KTILE_SH + wk * 2048;

    // ---- Q fragments: load fp32 directly, hi/lo convert in-register ----
    // (identical fp32->f16 ops as the old prep -> bitwise-equal fragments)
    f16x8 qh[4][2], ql[4][2];
#pragma unroll
    for (int m = 0; m < 4; ++m)
#pragma unroll
        for (int dh = 0; dh < 2; ++dh) {
            const float* qp = Qf + hoff + (size_t)(q0 + m * 16 + lj) * DH + dh * 32 + lg * 8;
            const float4 a = *(const float4*)qp;
            const float4 b = *(const float4*)(qp + 4);
            const float x[8] = {a.x,a.y,a.z,a.w, b.x,b.y,b.z,b.w};
            f16x8 hv, lv;
#pragma unroll
            for (int j = 0; j < 8; ++j) {
                _Float16 h = (_Float16)x[j];
                hv[j] = h;
                lv[j] = (_Float16)(x[j] - (float)h);
            }
            qh[m][dh] = hv;
            ql[m][dh] = lv;
        }

    int pmq[4];
#pragma unroll
    for (int r = 0; r < 4; ++r)
        pmq[r] = PM[(head >> 4) * 64 + wk * 16 + lg * 4 + r];

    // =============== PASS 1: rowsums + PV with unnormalized f16(e) — no barriers ===============
    float rs[4] = {0.f, 0.f, 0.f, 0.f};
    f32x4 ov[4][4];
#pragma unroll
    for (int m = 0; m < 4; ++m)
#pragma unroll
        for (int dt = 0; dt < 4; ++dt) ov[m][dt] = (f32x4){0.f,0.f,0.f,0.f};

    KF kfA, kfB;
    VF vfA, vfB;
    LDKF(kfA, 0);
    LDVF(vfA, 0);
#pragma unroll 1
    for (int it = 0; it < NKT / 2; ++it) {
        const int kt0 = it * 2, kt1 = kt0 + 1;
        LDKF(kfB, kt1);                 // prefetch next tile while body0 computes
        LDVF(vfB, kt1);
        P1BODY(kt0, kfA, vfA);
        LDKF(kfA, (kt1 + 1) & (NKT - 1));
        LDVF(vfA, (kt1 + 1) & (NKT - 1));
        P1BODY(kt1, kfB, vfB);
    }

    // ---- rowsum: lane-local q (=lj) -> sum over lg groups, then wk via LDS ----
#pragma unroll
    for (int m = 0; m < 4; ++m) {
        float v = rs[m];
        v += __shfl_xor(v, 16, 64);
        v += __shfl_xor(v, 32, 64);
        rs[m] = v;
    }
    if (lg == 0) {
#pragma unroll
        for (int m = 0; m < 4; ++m)
            s_red[m * 16 + lj][wk] = rs[m];
    }
    // ---- O partials (unscaled) ----
#pragma unroll
    for (int m = 0; m < 4; ++m)
#pragma unroll
        for (int dt = 0; dt < 4; ++dt)
#pragma unroll
            for (int r = 0; r < 4; ++r)
                s_op[wk][m * 16 + lg * 4 + r][dt * 16 + lj] = ov[m][dt][r];
    __syncthreads();   // the ONLY block barrier

    // ---- final O: combine 4 wk partials, scale by 1/rowsum, store ----
    {
        const int q  = t >> 2;
        const int c0 = (t & 3) * 16;
        const float inv = 1.0f / (s_red[q][0] + s_red[q][1] + s_red[q][2] + s_red[q][3]);
        float* op = out_res + hoff + (size_t)(q0 + q) * DH + c0;
#pragma unroll
        for (int g = 0; g < 4; ++g) {
            float4 o;
            o.x = (s_op[0][q][c0+g*4+0]+s_op[1][q][c0+g*4+0]+s_op[2][q][c0+g*4+0]+s_op[3][q][c0+g*4+0]) * inv;
            o.y = (s_op[0][q][c0+g*4+1]+s_op[1][q][c0+g*4+1]+s_op[2][q][c0+g*4+1]+s_op[3][q][c0+g*4+1]) * inv;
            o.z = (s_op[0][q][c0+g*4+2]+s_op[1][q][c0+g*4+2]+s_op[2][q][c0+g*4+2]+s_op[3][q][c0+g*4+2]) * inv;
            o.w = (s_op[0][q][c0+g*4+3]+s_op[1][q][c0+g*4+3]+s_op[2][q][c0+g*4+3]+s_op[3][q][c0+g*4+3]) * inv;
            *(float4*)(op + g * 4) = o;
        }
    }

    // =============== PASS 2: recompute e (identical), store normalized W — no barriers ===============
    float invr[4];
    size_t wbm[4];
#pragma unroll
    for (int m = 0; m < 4; ++m) {
        const int qq = m * 16 + lj;
        invr[m] = 1.0f / (s_red[qq][0] + s_red[qq][1] + s_red[qq][2] + s_red[qq][3]);
        wbm[m]  = woff + (size_t)(q0 + qq) * SEQ;
    }

    LDKF(kfA, 0);
#pragma unroll 1
    for (int it = 0; it < NKT / 2; ++it) {
        const int kt0 = it * 2, kt1 = kt0 + 1;
        LDKF(kfB, kt1);
        P2BODY(kt0, kfA);
        LDKF(kfA, (kt1 + 1) & (NKT - 1));
        P2BODY(kt1, kfB);
    }
}

extern "C" void kernel_launch(void* const* d_in, const int* in_sizes, int n_in,
                              void* d_out, int out_size, void* d_ws, size_t ws_size,
                              hipStream_t stream) {
    const float* Q   = (const float*)d_in[0];
    const float* K   = (const float*)d_in[1];
    const float* V   = (const float*)d_in[2];
    const int*   pad = (const int*)d_in[3];
    float* out_res = (float*)d_out;
    float* out_w   = out_res + (size_t)NB * NH * SEQ * DH;

    short* kimg = (short*)d_ws;                               // 33.5 MB
    short* vimg = kimg + (size_t)NHEADS * NKT * KTILE_SH;     // 33.5 MB
    unsigned* pm = (unsigned*)(vimg + (size_t)NHEADS * NKT * KTILE_SH);  // 1 KB

    prep<<<dim3(NHEADS * NKT), 256, 0, stream>>>(K, V, pad, kimg, vimg, pm);
    attn_fwd<<<dim3(NBLK), 256, 0, stream>>>(Q, kimg, vimg, pm, out_res, out_w);
}

// Round 10
// 1290.720 us; speedup vs baseline: 1.1257x; 1.1257x over previous
//
#include <hip/hip_runtime.h>

#define SEQ 2048
#define DH  64
#define NH  16
#define NB  4
#define NHEADS (NB * NH)            // 64
#define NKT 32                      // k-tiles of 64 keys
#define QT  64                      // q-rows per block
#define NQT (SEQ / QT)              // 32 q-tiles per head
#define NBLK (NHEADS * NQT)         // 2048 blocks
#define KTILE_SH 8192               // shorts per K/V tile image (64x64 hi+lo)

typedef _Float16 f16x8 __attribute__((ext_vector_type(8)));
typedef _Float16 f16x4 __attribute__((ext_vector_type(4)));
typedef short    s16x8 __attribute__((ext_vector_type(8)));
typedef float    f32x4 __attribute__((ext_vector_type(4)));

#define MF32(a,b,c) __builtin_amdgcn_mfma_f32_16x16x32_f16(a,b,c,0,0,0)
#define MF16(a,b,c) __builtin_amdgcn_mfma_f32_16x16x16f16(a,b,c,0,0,0)

static __device__ __forceinline__ short f16b(float x) {
    _Float16 h = (_Float16)x;
    return __builtin_bit_cast(short, h);
}

// ------------- prep: pack K,V into fragment-ordered f16 hi/lo images -------------
// kimg tile: [kg 4][dh 2][hl 2][lane 64][8]   (A-frag of swapped QK: row=key=lj, k=d)
// vimg tile: [kc 4][dt 4][lane 64][hi 4 | lo 4]  (B-frag of PV: col=d=lj, k=lg*4+j)
__global__ __launch_bounds__(256) void prep(
    const float* __restrict__ K, const float* __restrict__ V,
    const int* __restrict__ pad,
    short* __restrict__ kimg, short* __restrict__ vimg, unsigned* __restrict__ pm)
{
    const int t    = threadIdx.x;
    const int kt   = blockIdx.x & (NKT - 1);
    const int head = blockIdx.x >> 5;
    const size_t rowbase = ((size_t)head * SEQ + (size_t)kt * 64) * DH;

    {   // ---- K frag-pack: thread owns (row = t>>2, 16 cols) ----
        const int row = t >> 2;
        const int c0  = (t & 3) * 16;
        const int lj  = row & 15;
        const float4* gp = (const float4*)(K + rowbase + (size_t)row * DH + c0);
        const float4 v0 = gp[0], v1 = gp[1], v2 = gp[2], v3 = gp[3];
        const float x[16] = {v0.x,v0.y,v0.z,v0.w, v1.x,v1.y,v1.z,v1.w,
                             v2.x,v2.y,v2.z,v2.w, v3.x,v3.y,v3.z,v3.w};
        short* tb = kimg + ((size_t)head * NKT + kt) * KTILE_SH + (row >> 4) * 2048;
#pragma unroll
        for (int cg = 0; cg < 2; ++cg) {
            const int col0 = c0 + cg * 8;
            const int dh = col0 >> 5, lg = (col0 & 31) >> 3;
            s16x8 hi8, lo8;
#pragma unroll
            for (int j = 0; j < 8; ++j) {
                const float xv = x[cg * 8 + j];
                _Float16 h = (_Float16)xv;
                hi8[j] = __builtin_bit_cast(short, h);
                lo8[j] = f16b(xv - (float)h);
            }
            *(s16x8*)&tb[dh * 1024 +       (lg * 16 + lj) * 8] = hi8;
            *(s16x8*)&tb[dh * 1024 + 512 + (lg * 16 + lj) * 8] = lo8;
        }
    }
    {   // ---- V frag-pack: thread = (kc = t>>6, lane l = t&63) ----
        const int kc = t >> 6, l = t & 63;
        const int lg = l >> 4, lj = l & 15;
        short* tb = vimg + ((size_t)head * NKT + kt) * KTILE_SH + kc * 2048;
#pragma unroll
        for (int dt = 0; dt < 4; ++dt) {
            s16x8 o;
#pragma unroll
            for (int j = 0; j < 4; ++j) {
                const float xv = V[rowbase + (size_t)(kc * 16 + lg * 4 + j) * DH + dt * 16 + lj];
                _Float16 h = (_Float16)xv;
                o[j]     = __builtin_bit_cast(short, h);
                o[4 + j] = f16b(xv - (float)h);
            }
            *(s16x8*)&tb[dt * 512 + l * 8] = o;
        }
    }
    if (blockIdx.x == 0) {   // pad bitmask: pm[b*64 + key_local] bit kt
        const int b = t >> 6, klc = t & 63;
        unsigned mword = 0;
#pragma unroll
        for (int kt2 = 0; kt2 < NKT; ++kt2)
            mword |= (unsigned)(pad[b * SEQ + kt2 * 64 + klc] & 1) << kt2;
        pm[t] = mword;
    }
}

struct KF { f16x8 h0, l0, h1, l1; };
struct VF { f16x8 v0, v1, v2, v3; };

#define LDKF(dst_, kt_) do {                                                   \
    const short* p_ = kb + (size_t)(kt_) * KTILE_SH;                           \
    dst_.h0 = *(const f16x8*)(p_ +        l * 8);                              \
    dst_.l0 = *(const f16x8*)(p_ +  512 + l * 8);                              \
    dst_.h1 = *(const f16x8*)(p_ + 1024 + l * 8);                              \
    dst_.l1 = *(const f16x8*)(p_ + 1536 + l * 8);                              \
} while (0)

#define LDVF(dst_, kt_) do {                                                   \
    const short* p_ = vb + (size_t)(kt_) * KTILE_SH;                           \
    dst_.v0 = *(const f16x8*)(p_ +        l * 8);                              \
    dst_.v1 = *(const f16x8*)(p_ +  512 + l * 8);                              \
    dst_.v2 = *(const f16x8*)(p_ + 1024 + l * 8);                              \
    dst_.v3 = *(const f16x8*)(p_ + 1536 + l * 8);                              \
} while (0)

// 24 MFMAs, 3-term split (kh*qh + kh*ql + kl*qh), 4 q-subtiles.
// SAME order in both passes (bitwise-equal e).
#define QK24(kf_, a0_, a1_, a2_, a3_) do {                                     \
    a0_ = MF32(kf_.h0, qh[0][0], a0_);  a1_ = MF32(kf_.h0, qh[1][0], a1_);     \
    a2_ = MF32(kf_.h0, qh[2][0], a2_);  a3_ = MF32(kf_.h0, qh[3][0], a3_);     \
    a0_ = MF32(kf_.h0, ql[0][0], a0_);  a1_ = MF32(kf_.h0, ql[1][0], a1_);     \
    a2_ = MF32(kf_.h0, ql[2][0], a2_);  a3_ = MF32(kf_.h0, ql[3][0], a3_);     \
    a0_ = MF32(kf_.l0, qh[0][0], a0_);  a1_ = MF32(kf_.l0, qh[1][0], a1_);     \
    a2_ = MF32(kf_.l0, qh[2][0], a2_);  a3_ = MF32(kf_.l0, qh[3][0], a3_);     \
    a0_ = MF32(kf_.h1, qh[0][1], a0_);  a1_ = MF32(kf_.h1, qh[1][1], a1_);     \
    a2_ = MF32(kf_.h1, qh[2][1], a2_);  a3_ = MF32(kf_.h1, qh[3][1], a3_);     \
    a0_ = MF32(kf_.h1, ql[0][1], a0_);  a1_ = MF32(kf_.h1, ql[1][1], a1_);     \
    a2_ = MF32(kf_.h1, ql[2][1], a2_);  a3_ = MF32(kf_.h1, ql[3][1], a3_);     \
    a0_ = MF32(kf_.l1, qh[0][1], a0_);  a1_ = MF32(kf_.l1, qh[1][1], a1_);     \
    a2_ = MF32(kf_.l1, qh[2][1], a2_);  a3_ = MF32(kf_.l1, qh[3][1], a3_);     \
} while (0)

#define P1BODY(kt_, kf_, vf_) do {                                             \
    f32x4 a0_ = (f32x4){0.f,0.f,0.f,0.f}, a1_ = (f32x4){0.f,0.f,0.f,0.f};      \
    f32x4 a2_ = (f32x4){0.f,0.f,0.f,0.f}, a3_ = (f32x4){0.f,0.f,0.f,0.f};      \
    QK24(kf_, a0_, a1_, a2_, a3_);                                             \
    const int kab_ = (kt_) * 64 + wk * 16 + lg * 4;                            \
    f16x4 w16_[4];                                                             \
    _Pragma("unroll") for (int m = 0; m < 4; ++m) {                            \
        const f32x4 av_ = (m==0) ? a0_ : (m==1) ? a1_ : (m==2) ? a2_ : a3_;    \
        const int qg_ = qglob + m * 16;                                        \
        float e_[4];                                                           \
        _Pragma("unroll") for (int r = 0; r < 4; ++r) {                        \
            const int ka_ = kab_ + r;                                          \
            const int pd_ = (int)((pmq[r] >> (kt_)) & 1u);                     \
            const bool msk_ = ((ka_ > qg_) != (pd_ == 1));                     \
            e_[r] = __expf((msk_ ? -8.0e9f : av_[r]) * 0.125f);                \
        }                                                                      \
        rs[m] += (e_[0] + e_[1]) + (e_[2] + e_[3]);                            \
        w16_[m] = (f16x4){(_Float16)e_[0], (_Float16)e_[1],                    \
                          (_Float16)e_[2], (_Float16)e_[3]};                   \
    }                                                                          \
    _Pragma("unroll") for (int dt = 0; dt < 4; ++dt) {                         \
        const f16x8 vv_ = (dt==0) ? vf_.v0 : (dt==1) ? vf_.v1                  \
                        : (dt==2) ? vf_.v2 : vf_.v3;                           \
        const f16x4 vh_ = __builtin_shufflevector(vv_, vv_, 0,1,2,3);          \
        const f16x4 vl_ = __builtin_shufflevector(vv_, vv_, 4,5,6,7);          \
        ov[0][dt] = MF16(w16_[0], vh_, ov[0][dt]);                             \
        ov[1][dt] = MF16(w16_[1], vh_, ov[1][dt]);                             \
        ov[2][dt] = MF16(w16_[2], vh_, ov[2][dt]);                             \
        ov[3][dt] = MF16(w16_[3], vh_, ov[3][dt]);                             \
        ov[0][dt] = MF16(w16_[0], vl_, ov[0][dt]);                             \
        ov[1][dt] = MF16(w16_[1], vl_, ov[1][dt]);                             \
        ov[2][dt] = MF16(w16_[2], vl_, ov[2][dt]);                             \
        ov[3][dt] = MF16(w16_[3], vl_, ov[3][dt]);                             \
    }                                                                          \
} while (0)

#define P2BODY(kt_, kf_) do {                                                  \
    f32x4 a0_ = (f32x4){0.f,0.f,0.f,0.f}, a1_ = (f32x4){0.f,0.f,0.f,0.f};      \
    f32x4 a2_ = (f32x4){0.f,0.f,0.f,0.f}, a3_ = (f32x4){0.f,0.f,0.f,0.f};      \
    QK24(kf_, a0_, a1_, a2_, a3_);                                             \
    const int kab_ = (kt_) * 64 + wk * 16 + lg * 4;                            \
    _Pragma("unroll") for (int m = 0; m < 4; ++m) {                            \
        const f32x4 av_ = (m==0) ? a0_ : (m==1) ? a1_ : (m==2) ? a2_ : a3_;    \
        const int qg_ = qglob + m * 16;                                        \
        float e_[4];                                                           \
        _Pragma("unroll") for (int r = 0; r < 4; ++r) {                        \
            const int ka_ = kab_ + r;                                          \
            const int pd_ = (int)((pmq[r] >> (kt_)) & 1u);                     \
            const bool msk_ = ((ka_ > qg_) != (pd_ == 1));                     \
            e_[r] = __expf((msk_ ? -8.0e9f : av_[r]) * 0.125f);                \
        }                                                                      \
        f32x4 w4_;                                                             \
        w4_[0] = e_[0] * invr[m]; w4_[1] = e_[1] * invr[m];                    \
        w4_[2] = e_[2] * invr[m]; w4_[3] = e_[3] * invr[m];                    \
        __builtin_nontemporal_store(w4_, (f32x4*)&out_w[wbm[m] + kab_]);       \
    }                                                                          \
} while (0)

__global__ __launch_bounds__(256, 2) void attn_fwd(
    const float* __restrict__ Qf, const short* __restrict__ KI,
    const short* __restrict__ VI, const unsigned* __restrict__ PM,
    float* __restrict__ out_res, float* __restrict__ out_w)
{
    __shared__ float s_op[4][QT][65];    // per-wk O partials (epilogue) ~66.6 KB
    __shared__ float s_red[QT][4];       // rowsum partials

    const int t = threadIdx.x;
    int bid = blockIdx.x;
    bid = (bid & 7) * (NBLK / 8) + (bid >> 3);       // XCD-chunked swizzle (2048%8==0)

    const int qtile = bid & (NQT - 1);
    const int head  = bid >> 5;                      // b*NH + h
    const int q0    = qtile * QT;
    const size_t hoff = (size_t)head * SEQ * DH;
    const size_t woff = (size_t)head * SEQ * SEQ;

    const int l  = t & 63;
    const int wk = t >> 6;        // wave = 16-key column group 0..3
    const int lj = l & 15;
    const int lg = l >> 4;
    const int qglob = q0 + lj;    // q row for m=0 (lane-local in swapped layout)

    const short* kb = KI + (size_t)head * NKT * KTILE_SH + wk * 2048;
    const short* vb = VI + (size_t)head * NKT * KTILE_SH + wk * 2048;

    // ---- Q fragments: load fp32 directly, hi/lo convert in-register ----
    f16x8 qh[4][2], ql[4][2];
#pragma unroll
    for (int m = 0; m < 4; ++m)
#pragma unroll
        for (int dh = 0; dh < 2; ++dh) {
            const float* qp = Qf + hoff + (size_t)(q0 + m * 16 + lj) * DH + dh * 32 + lg * 8;
            const float4 a = *(const float4*)qp;
            const float4 b = *(const float4*)(qp + 4);
            const float x[8] = {a.x,a.y,a.z,a.w, b.x,b.y,b.z,b.w};
            f16x8 hv, lv;
#pragma unroll
            for (int j = 0; j < 8; ++j) {
                _Float16 h = (_Float16)x[j];
                hv[j] = h;
                lv[j] = (_Float16)(x[j] - (float)h);
            }
            qh[m][dh] = hv;
            ql[m][dh] = lv;
        }

    int pmq[4];
#pragma unroll
    for (int r = 0; r < 4; ++r)
        pmq[r] = PM[(head >> 4) * 64 + wk * 16 + lg * 4 + r];

    // =============== PASS 1: rowsums + PV with unnormalized f16(e) — no barriers ===============
    float rs[4] = {0.f, 0.f, 0.f, 0.f};
    f32x4 ov[4][4];
#pragma unroll
    for (int m = 0; m < 4; ++m)
#pragma unroll
        for (int dt = 0; dt < 4; ++dt) ov[m][dt] = (f32x4){0.f,0.f,0.f,0.f};

    KF kfA, kfB;
    VF vfA, vfB;
    LDKF(kfA, 0);
    LDVF(vfA, 0);
#pragma unroll 1
    for (int it = 0; it < NKT / 2; ++it) {
        const int kt0 = it * 2, kt1 = kt0 + 1;
        LDKF(kfB, kt1);                 // prefetch next tile while body0 computes
        LDVF(vfB, kt1);
        P1BODY(kt0, kfA, vfA);
        LDKF(kfA, (kt1 + 1) & (NKT - 1));
        LDVF(vfA, (kt1 + 1) & (NKT - 1));
        P1BODY(kt1, kfB, vfB);
    }

    // ---- rowsum: lane-local q (=lj) -> sum over lg groups, then wk via LDS ----
#pragma unroll
    for (int m = 0; m < 4; ++m) {
        float v = rs[m];
        v += __shfl_xor(v, 16, 64);
        v += __shfl_xor(v, 32, 64);
        rs[m] = v;
    }
    if (lg == 0) {
#pragma unroll
        for (int m = 0; m < 4; ++m)
            s_red[m * 16 + lj][wk] = rs[m];
    }
    // ---- O partials (unscaled) ----
#pragma unroll
    for (int m = 0; m < 4; ++m)
#pragma unroll
        for (int dt = 0; dt < 4; ++dt)
#pragma unroll
            for (int r = 0; r < 4; ++r)
                s_op[wk][m * 16 + lg * 4 + r][dt * 16 + lj] = ov[m][dt][r];
    __syncthreads();   // the ONLY block barrier

    // ---- final O: combine 4 wk partials, scale by 1/rowsum, store ----
    {
        const int q  = t >> 2;
        const int c0 = (t & 3) * 16;
        const float inv = 1.0f / (s_red[q][0] + s_red[q][1] + s_red[q][2] + s_red[q][3]);
        float* op = out_res + hoff + (size_t)(q0 + q) * DH + c0;
#pragma unroll
        for (int g = 0; g < 4; ++g) {
            float4 o;
            o.x = (s_op[0][q][c0+g*4+0]+s_op[1][q][c0+g*4+0]+s_op[2][q][c0+g*4+0]+s_op[3][q][c0+g*4+0]) * inv;
            o.y = (s_op[0][q][c0+g*4+1]+s_op[1][q][c0+g*4+1]+s_op[2][q][c0+g*4+1]+s_op[3][q][c0+g*4+1]) * inv;
            o.z = (s_op[0][q][c0+g*4+2]+s_op[1][q][c0+g*4+2]+s_op[2][q][c0+g*4+2]+s_op[3][q][c0+g*4+2]) * inv;
            o.w = (s_op[0][q][c0+g*4+3]+s_op[1][q][c0+g*4+3]+s_op[2][q][c0+g*4+3]+s_op[3][q][c0+g*4+3]) * inv;
            *(float4*)(op + g * 4) = o;
        }
    }

    // =============== PASS 2: recompute e (identical), store normalized W — no barriers ===============
    float invr[4];
    size_t wbm[4];
#pragma unroll
    for (int m = 0; m < 4; ++m) {
        const int qq = m * 16 + lj;
        invr[m] = 1.0f / (s_red[qq][0] + s_red[qq][1] + s_red[qq][2] + s_red[qq][3]);
        wbm[m]  = woff + (size_t)(q0 + qq) * SEQ;
    }

    LDKF(kfA, 0);
#pragma unroll 1
    for (int it = 0; it < NKT / 2; ++it) {
        const int kt0 = it * 2, kt1 = kt0 + 1;
        LDKF(kfB, kt1);
        P2BODY(kt0, kfA);
        LDKF(kfA, (kt1 + 1) & (NKT - 1));
        P2BODY(kt1, kfB);
    }
}

extern "C" void kernel_launch(void* const* d_in, const int* in_sizes, int n_in,
                              void* d_out, int out_size, void* d_ws, size_t ws_size,
                              hipStream_t stream) {
    const float* Q   = (const float*)d_in[0];
    const float* K   = (const float*)d_in[1];
    const float* V   = (const float*)d_in[2];
    const int*   pad = (const int*)d_in[3];
    float* out_res = (float*)d_out;
    float* out_w   = out_res + (size_t)NB * NH * SEQ * DH;

    short* kimg = (short*)d_ws;                               // 33.5 MB
    short* vimg = kimg + (size_t)NHEADS * NKT * KTILE_SH;     // 33.5 MB
    unsigned* pm = (unsigned*)(vimg + (size_t)NHEADS * NKT * KTILE_SH);  // 1 KB

    prep<<<dim3(NHEADS * NKT), 256, 0, stream>>>(K, V, pad, kimg, vimg, pm);
    attn_fwd<<<dim3(NBLK), 256, 0, stream>>>(Q, kimg, vimg, pm, out_res, out_w);
}